// Round 1
// baseline (5543.901 us; speedup 1.0000x reference)
//
#include <hip/hip_runtime.h>
#include <math.h>

#define S_LEN 2048
#define HD 512
#define G4 2048      // 4*HD gate rows
#define E_DIM 512
#define NTAG 12
#define TAG_START 10
#define TAG_STOP 11
#define NEGV -10000.0f

static constexpr unsigned SENTI = 0x7fb0deadu;   // NaN bit pattern; h in (-1,1) can never equal it

// ---------------- init: fill h buffers with sentinel ----------------
__global__ void init_k(unsigned* __restrict__ p, int n)
{
    int i = blockIdx.x * blockDim.x + threadIdx.x;
    if (i < n) p[i] = SENTI;
}

// ---------------- X pre-GEMM: X[dir][t][row] = emb[t].Wih[row] + bih[row]+bhh[row] ----------------
#define BK 16
__global__ __launch_bounds__(256) void xgemm_k(
    const int* __restrict__ sent, const float* __restrict__ embed,
    const float* __restrict__ WihF, const float* __restrict__ WihB,
    const float* __restrict__ bihF, const float* __restrict__ bhhF,
    const float* __restrict__ bihB, const float* __restrict__ bhhB,
    float* __restrict__ Xf, float* __restrict__ Xb)
{
    const int dir = blockIdx.z;
    const float* __restrict__ Wih = dir ? WihB : WihF;
    const float* __restrict__ bih = dir ? bihB : bihF;
    const float* __restrict__ bhh = dir ? bhhB : bhhF;
    float* __restrict__ X = dir ? Xb : Xf;

    const int m0 = blockIdx.y * 64;   // t tile
    const int n0 = blockIdx.x * 64;   // gate-row tile
    const int tid = threadIdx.x;

    __shared__ float At[BK][68];      // transposed tiles: [k][row], pad 68
    __shared__ float Bt[BK][68];

    const int lr = tid >> 2;          // 0..63 staging row
    const int lc = (tid & 3) * 4;     // k sub-offset
    const float* __restrict__ arow = embed + (size_t)sent[m0 + lr] * E_DIM + lc;
    const float* __restrict__ brow = Wih + (size_t)(n0 + lr) * E_DIM + lc;

    const int tx = tid & 15, ty = tid >> 4;
    float acc[4][4] = {};

    for (int kt = 0; kt < E_DIM; kt += BK) {
        const float4 av = *(const float4*)(arow + kt);
        const float4 bv = *(const float4*)(brow + kt);
        __syncthreads();
        At[lc+0][lr] = av.x; At[lc+1][lr] = av.y; At[lc+2][lr] = av.z; At[lc+3][lr] = av.w;
        Bt[lc+0][lr] = bv.x; Bt[lc+1][lr] = bv.y; Bt[lc+2][lr] = bv.z; Bt[lc+3][lr] = bv.w;
        __syncthreads();
        #pragma unroll
        for (int kk = 0; kk < BK; ++kk) {
            const float4 a4 = *(const float4*)&At[kk][ty*4];
            const float4 b4 = *(const float4*)&Bt[kk][tx*4];
            const float a_[4] = {a4.x, a4.y, a4.z, a4.w};
            const float b_[4] = {b4.x, b4.y, b4.z, b4.w};
            #pragma unroll
            for (int i = 0; i < 4; ++i)
                #pragma unroll
                for (int j = 0; j < 4; ++j)
                    acc[i][j] += a_[i] * b_[j];
        }
    }
    float bias[4];
    #pragma unroll
    for (int j = 0; j < 4; ++j) {
        int col = n0 + tx*4 + j;
        bias[j] = bih[col] + bhh[col];
    }
    #pragma unroll
    for (int i = 0; i < 4; ++i) {
        int t = m0 + ty*4 + i;
        float4 o;
        o.x = acc[i][0] + bias[0];
        o.y = acc[i][1] + bias[1];
        o.z = acc[i][2] + bias[2];
        o.w = acc[i][3] + bias[3];
        *(float4*)(X + (size_t)t * G4 + n0 + tx*4) = o;
    }
}

// ---------------- recurrence: 64 blocks/direction, weights in VGPRs, sentinel sync ----------------
#define NB 64
#define UPB 8        // hidden units per block
#define CHUNK 64     // h columns per thread

__global__ __launch_bounds__(256, 1) void lstm_rec(
    const float* __restrict__ WhhF, const float* __restrict__ WhhB,
    const float* __restrict__ Xf, const float* __restrict__ Xb,
    const float* __restrict__ h0, const float* __restrict__ c0,
    float* __restrict__ hfp, float* __restrict__ hbp)
{
    const int bid = blockIdx.x;
    const int dir = bid >> 6;          // 0 fwd, 1 bwd
    const int b   = bid & 63;
    const float* __restrict__ Whh = dir ? WhhB : WhhF;
    const float* __restrict__ X   = dir ? Xb : Xf;
    unsigned* __restrict__ Hu = (unsigned*)(dir ? hbp : hfp);

    const int tid = threadIdx.x;
    const int r = tid >> 3;            // 0..31 local gate-row
    const int k = tid & 7;             // column chunk
    const int ul = r >> 2;             // 0..7 local unit
    const int g = r & 3;               // gate (i,f,g,o)
    const int unit = b * UPB + ul;
    const int row_g = g * HD + unit;   // global gate row in [0,2048)

    // 64 weights per thread, held in VGPRs for the whole kernel
    float w[CHUNK];
    {
        const float4* wp = (const float4*)(Whh + (size_t)row_g * HD + k * CHUNK);
        #pragma unroll
        for (int j = 0; j < CHUNK/4; ++j) {
            float4 v = wp[j];
            w[4*j+0] = v.x; w[4*j+1] = v.y; w[4*j+2] = v.z; w[4*j+3] = v.w;
        }
    }

    __shared__ float hlds[8 * 68];     // 8 chunks of 64, padded stride 68 (16B aligned, conflict-free)

    const int l  = tid & 63;
    const int l0 = l & 32;             // unit-group base within wave
    const bool cellln = (l & 31) == 0; // one lane per unit does the cell update
    float c = cellln ? c0[dir*HD + unit] : 0.f;

    for (int s = 0; s < S_LEN; ++s) {
        const int t_io = dir ? (S_LEN-1-s) : s;
        // prefetch X early (independent of h wait)
        float xval = 0.f;
        if (k == 0) xval = X[(size_t)t_io * G4 + row_g];

        if (s == 0) {
            float2 hv = *(const float2*)(h0 + dir*HD + tid*2);
            int ch = tid >> 5, off = (tid*2) & 63;
            hlds[ch*68 + off]   = hv.x;
            hlds[ch*68 + off+1] = hv.y;
        } else {
            const int prev = dir ? (t_io+1) : (t_io-1);
            const unsigned long long* src =
                (const unsigned long long*)(Hu + (size_t)prev*HD) + tid;
            unsigned long long v;
            do {
                v = __hip_atomic_load(src, __ATOMIC_RELAXED, __HIP_MEMORY_SCOPE_AGENT);
            } while ((unsigned)v == SENTI || (unsigned)(v >> 32) == SENTI);
            int ch = tid >> 5, off = (tid*2) & 63;
            hlds[ch*68 + off]   = __uint_as_float((unsigned)v);
            hlds[ch*68 + off+1] = __uint_as_float((unsigned)(v >> 32));
        }
        __syncthreads();

        // 64-wide dot chunk
        float acc = 0.f;
        const float* __restrict__ hp = &hlds[k * 68];
        #pragma unroll
        for (int j = 0; j < CHUNK/4; ++j) {
            const float4 hv = *(const float4*)(hp + 4*j);
            acc += w[4*j+0]*hv.x;
            acc += w[4*j+1]*hv.y;
            acc += w[4*j+2]*hv.z;
            acc += w[4*j+3]*hv.w;
        }
        // reduce across the 8 chunk lanes
        acc += __shfl_xor(acc, 1);
        acc += __shfl_xor(acc, 2);
        acc += __shfl_xor(acc, 4);
        const float pre = acc + xval;          // valid at k==0 lanes

        // branchless activation: sigmoid for i,f,o; tanh (=2*sig(2x)-1) for g
        const float yy  = (g == 2) ? 2.f*pre : pre;
        const float sg  = 1.f / (1.f + __expf(-yy));
        const float act = (g == 2) ? 2.f*sg - 1.f : sg;

        const float a_i = __shfl(act, l0 + 0);
        const float a_f = __shfl(act, l0 + 8);
        const float a_g = __shfl(act, l0 + 16);
        const float a_o = __shfl(act, l0 + 24);
        if (cellln) {
            c = a_f*c + a_i*a_g;
            const float th = 2.f / (1.f + __expf(-2.f*c)) - 1.f;
            const float h = a_o * th;
            __hip_atomic_store(Hu + (size_t)t_io*HD + unit, __float_as_uint(h),
                               __ATOMIC_RELAXED, __HIP_MEMORY_SCOPE_AGENT);
        }
        __syncthreads();   // protect hlds before next staging
    }
}

// ---------------- feats: [hf,hb] @ Wout.T + bout ----------------
__global__ __launch_bounds__(256) void feats_k(
    const float* __restrict__ hf, const float* __restrict__ hb,
    const float* __restrict__ Wout, const float* __restrict__ bout,
    float* __restrict__ feats)
{
    int idx = blockIdx.x * blockDim.x + threadIdx.x;
    if (idx >= S_LEN * NTAG) return;
    int t = idx / NTAG, tag = idx - t*NTAG;
    const float* __restrict__ wf  = Wout + (size_t)tag * (2*HD);
    const float* __restrict__ ha  = hf + (size_t)t * HD;
    const float* __restrict__ hbr = hb + (size_t)t * HD;
    float a0=0.f, a1=0.f, a2=0.f, a3=0.f;
    for (int i = 0; i < HD; i += 4) {
        float4 h4 = *(const float4*)(ha + i);
        float4 w4 = *(const float4*)(wf + i);
        a0 += h4.x*w4.x; a1 += h4.y*w4.y; a2 += h4.z*w4.z; a3 += h4.w*w4.w;
    }
    for (int i = 0; i < HD; i += 4) {
        float4 h4 = *(const float4*)(hbr + i);
        float4 w4 = *(const float4*)(wf + HD + i);
        a0 += h4.x*w4.x; a1 += h4.y*w4.y; a2 += h4.z*w4.z; a3 += h4.w*w4.w;
    }
    feats[idx] = a0+a1+a2+a3 + bout[tag];
}

// ---------------- Viterbi forward + backtrace, single block ----------------
__global__ __launch_bounds__(256, 1) void viterbi_k(
    const float* __restrict__ feats, const float* __restrict__ trans,
    float* __restrict__ out)
{
    __shared__ float fl[S_LEN * NTAG];           // 96 KB
    __shared__ unsigned char bpl[S_LEN * NTAG];  // 24 KB
    {
        const float4* src = (const float4*)feats;
        float4* dst = (float4*)fl;
        for (int i = threadIdx.x; i < S_LEN*NTAG/4; i += 256) dst[i] = src[i];
    }
    __syncthreads();
    if (threadIdx.x < 64) {
        const int ln = threadIdx.x;
        if (ln < NTAG) {
            float tr[NTAG];
            #pragma unroll
            for (int p = 0; p < NTAG; ++p) tr[p] = trans[ln*NTAG + p];
            float fv = (ln == TAG_START) ? 0.f : NEGV;
            for (int t = 0; t < S_LEN; ++t) {
                float best = -3.4e38f; int arg = 0;
                #pragma unroll
                for (int p = 0; p < NTAG; ++p) {
                    float sc = __shfl(fv, p) + tr[p];
                    if (sc > best) { best = sc; arg = p; }   // strict > = first-max (np argmax)
                }
                bpl[t*NTAG + ln] = (unsigned char)arg;
                fv = best + fl[t*NTAG + ln];
            }
            float tsc = fv + trans[TAG_STOP*NTAG + ln];
            float bestt = -3.4e38f; int argt = 0;
            #pragma unroll
            for (int p = 0; p < NTAG; ++p) {
                float v = __shfl(tsc, p);
                if (v > bestt) { bestt = v; argt = p; }
            }
            if (ln == 0) {
                out[0] = bestt;
                int tag = argt;
                for (int t = S_LEN-1; t >= 0; --t) {
                    out[1+t] = (float)tag;
                    tag = bpl[t*NTAG + tag];
                }
            }
        }
    }
}

// ---------------- launch ----------------
extern "C" void kernel_launch(void* const* d_in, const int* in_sizes, int n_in,
                              void* d_out, int out_size, void* d_ws, size_t ws_size,
                              hipStream_t stream)
{
    const int*   sent  = (const int*)d_in[0];
    const float* embed = (const float*)d_in[1];
    const float* WihF  = (const float*)d_in[2];
    const float* WhhF  = (const float*)d_in[3];
    const float* bihF  = (const float*)d_in[4];
    const float* bhhF  = (const float*)d_in[5];
    const float* WihB  = (const float*)d_in[6];
    const float* WhhB  = (const float*)d_in[7];
    const float* bihB  = (const float*)d_in[8];
    const float* bhhB  = (const float*)d_in[9];
    const float* h0    = (const float*)d_in[10];
    const float* c0    = (const float*)d_in[11];
    const float* Wout  = (const float*)d_in[12];
    const float* bout  = (const float*)d_in[13];
    const float* trans = (const float*)d_in[14];
    float* out = (float*)d_out;

    float* ws = (float*)d_ws;
    float* Xf = ws;
    float* Xb = Xf + (size_t)S_LEN * G4;
    float* hf = Xb + (size_t)S_LEN * G4;
    float* hb = hf + (size_t)S_LEN * HD;
    float* feats = hb + (size_t)S_LEN * HD;

    // 1) sentinel-fill both h buffers (2*2048*512 words)
    {
        int n = 2 * S_LEN * HD;
        init_k<<<(n + 255)/256, 256, 0, stream>>>((unsigned*)hf, n);
    }
    // 2) X pre-GEMM for both directions
    {
        dim3 grid(G4/64, S_LEN/64, 2);
        xgemm_k<<<grid, 256, 0, stream>>>(sent, embed, WihF, WihB,
                                          bihF, bhhF, bihB, bhhB, Xf, Xb);
    }
    // 3) recurrence, both directions concurrently
    lstm_rec<<<2*NB, 256, 0, stream>>>(WhhF, WhhB, Xf, Xb, h0, c0, hf, hb);
    // 4) emission features
    {
        int n = S_LEN * NTAG;
        feats_k<<<(n + 255)/256, 256, 0, stream>>>(hf, hb, Wout, bout, feats);
    }
    // 5) Viterbi decode
    viterbi_k<<<1, 256, 0, stream>>>(feats, trans, out);
}